// Round 1
// baseline (698.772 us; speedup 1.0000x reference)
//
#include <hip/hip_runtime.h>
#include <hip/hip_bf16.h>
#include <hip/hip_fp16.h>
#include <math.h>

// Causal conv via four-step FFT, N = 2T = 131072 = N1(512) x N2(256).
// z = bf16(x) + i*h ; one complex FFT serves both real signals.
// n = n1 + 512*n2 (n1 in [0,512), n2 in [0,256), nonzero n2 < 128).
// buf[seq][k2][n1] half2, k2 NATURAL order (256 rows x 512).
// ws: [0,1MiB) cpx tw[m] = exp(-2pi i m/N); [2MiB,+256MiB) buf.
//
// R1: packed-FP32 complex arithmetic (VOP3P v_pk_*_f32) + table twiddles
// (no __sincosf anywhere) + scale folding (0.25*invN into final twiddle).

#define TLEN 65536
#define NFFT 131072
#define NN1 512
#define NN2 256

#define WFENCE() asm volatile("s_waitcnt lgkmcnt(0)" ::: "memory")

typedef float cpx __attribute__((ext_vector_type(2)));

static __device__ __forceinline__ cpx mkc(float a, float b) { cpx r; r.x = a; r.y = b; return r; }
static __device__ __forceinline__ cpx h2c(__half2 h) { float2 f = __half22float2(h); return mkc(f.x, f.y); }
static __device__ __forceinline__ __half2 c2h(cpx c) { return __float22half2_rn(make_float2(c.x, c.y)); }

// ---- packed complex primitives (one VOP3P inst per complex add/sub) ----
static __device__ __forceinline__ cpx cadd(cpx a, cpx b) {
  cpx d; asm("v_pk_add_f32 %0, %1, %2" : "=v"(d) : "v"(a), "v"(b)); return d;
}
static __device__ __forceinline__ cpx csub(cpx a, cpx b) {
  cpx d; asm("v_pk_add_f32 %0, %1, %2 neg_lo:[0,1] neg_hi:[0,1]" : "=v"(d) : "v"(a), "v"(b)); return d;
}
static __device__ __forceinline__ cpx cscale(cpx a, cpx c) {
  cpx d; asm("v_pk_mul_f32 %0, %1, %2" : "=v"(d) : "v"(a), "v"(c)); return d;
}
// d = a*b : t = (a.x*b.x, a.x*b.y); d = (-a.y*b.y + t.lo, a.y*b.x + t.hi)
static __device__ __forceinline__ cpx cmul(cpx a, cpx b) {
  cpx t, d;
  asm("v_pk_mul_f32 %0, %1, %2 op_sel:[0,0] op_sel_hi:[0,1]" : "=v"(t) : "v"(a), "v"(b));
  asm("v_pk_fma_f32 %0, %1, %2, %3 op_sel:[1,1,0] op_sel_hi:[1,0,1] neg_lo:[1,0,0]"
      : "=v"(d) : "v"(a), "v"(b), "v"(t));
  return d;
}
// d = a*conj(b) : (a.x b.x + a.y b.y, a.y b.x - a.x b.y)
static __device__ __forceinline__ cpx cmulc(cpx a, cpx b) {
  cpx t, d;
  asm("v_pk_mul_f32 %0, %1, %2 op_sel:[0,0] op_sel_hi:[0,1]" : "=v"(t) : "v"(a), "v"(b));
  asm("v_pk_fma_f32 %0, %1, %2, %3 op_sel:[1,1,0] op_sel_hi:[1,0,1] neg_hi:[0,0,1]"
      : "=v"(d) : "v"(a), "v"(b), "v"(t));
  return d;
}
// d = s*i*a : S=+1 -> (-a.y, a.x) ; S=-1 -> (a.y, -a.x)
template <int S> static __device__ __forceinline__ cpx cmuli(cpx a) {
  cpx z = mkc(0.f, 0.f); cpx d;
  if constexpr (S == 1)
    asm("v_pk_add_f32 %0, %1, %2 op_sel:[1,0] op_sel_hi:[0,0] neg_lo:[1,0]" : "=v"(d) : "v"(a), "v"(z));
  else
    asm("v_pk_add_f32 %0, %1, %2 op_sel:[1,0] op_sel_hi:[0,0] neg_hi:[1,0]" : "=v"(d) : "v"(a), "v"(z));
  return d;
}
// C * (d.x - s d.y, s d.x + d.y)
template <int S> static __device__ __forceinline__ cpx cw1(cpx d, cpx Cc) {
  cpx u;
  if constexpr (S == -1)
    asm("v_pk_add_f32 %0, %1, %1 op_sel:[0,1] op_sel_hi:[1,0] neg_hi:[0,1]" : "=v"(u) : "v"(d));
  else
    asm("v_pk_add_f32 %0, %1, %1 op_sel:[0,1] op_sel_hi:[0,1] neg_lo:[0,1]" : "=v"(u) : "v"(d));
  return cscale(u, Cc);
}
// C * (-d.x - s d.y, s d.x - d.y)
template <int S> static __device__ __forceinline__ cpx cw3(cpx d, cpx Cc) {
  cpx u;
  if constexpr (S == -1)
    asm("v_pk_add_f32 %0, %1, %1 op_sel:[1,0] op_sel_hi:[0,1] neg_lo:[0,1] neg_hi:[1,1]" : "=v"(u) : "v"(d));
  else
    asm("v_pk_add_f32 %0, %1, %1 op_sel:[0,1] op_sel_hi:[0,1] neg_lo:[1,1] neg_hi:[0,1]" : "=v"(u) : "v"(d));
  return cscale(u, Cc);
}

// out[k] = sum_j in[j] * W8^{S*jk}, W8 = e^{-2pi i/8}. Natural order.
template <int S>
__device__ __forceinline__ void fft8(cpx v[8]) {
  cpx Cc; Cc.x = 0.70710678118654752f; Cc.y = 0.70710678118654752f;
  cpx b0 = cadd(v[0], v[4]), b4 = csub(v[0], v[4]);
  cpx b1 = cadd(v[1], v[5]), d1 = csub(v[1], v[5]);
  cpx b2 = cadd(v[2], v[6]), d2 = csub(v[2], v[6]);
  cpx b3 = cadd(v[3], v[7]), d3 = csub(v[3], v[7]);
  cpx b5 = cw1<S>(d1, Cc);
  cpx b6 = cmuli<S>(d2);
  cpx b7 = cw3<S>(d3, Cc);
  cpx c0 = cadd(b0, b2), c2 = csub(b0, b2);
  cpx c1 = cadd(b1, b3), e3 = csub(b1, b3);
  cpx c3 = cmuli<S>(e3);
  cpx c4 = cadd(b4, b6), c6 = csub(b4, b6);
  cpx c5 = cadd(b5, b7), e7 = csub(b5, b7);
  cpx c7 = cmuli<S>(e7);
  v[0] = cadd(c0, c1); v[4] = csub(c0, c1);
  v[2] = cadd(c2, c3); v[6] = csub(c2, c3);
  v[1] = cadd(c4, c5); v[5] = csub(c4, c5);
  v[3] = cadd(c6, c7); v[7] = csub(c6, c7);
}

template <int S>
__device__ __forceinline__ void fft4(cpx v[4]) {
  cpx t0 = cadd(v[0], v[2]), t1 = csub(v[0], v[2]);
  cpx t2 = cadd(v[1], v[3]), t3 = csub(v[1], v[3]);
  cpx it3 = cmuli<S>(t3);
  v[0] = cadd(t0, t2); v[2] = csub(t0, t2);
  v[1] = cadd(t1, it3); v[3] = csub(t1, it3);
}

__global__ void k_init_tw(cpx* __restrict__ tw) {
  int m = blockIdx.x * 256 + threadIdx.x;
  double ang = (double)m * (-2.0 * 3.14159265358979323846 / (double)NFFT);
  tw[m] = mkc((float)cos(ang), (float)sin(ang));
}

// ---------------------------------------------------------------------------
// K1: forward FFT-256 over n2 for 16 n1 per block + twiddle W_N^{n1 k2}.
// Register FFT 256 = 8x8x4: fft8(regs), E1, fft8(regs), E2, fft4(regs).
// Big twiddle from tw[] table: k2 = c0 + 32*(g + 2*k1q); base*step^m chain.
// ---------------------------------------------------------------------------
__global__ __launch_bounds__(256, 3) void k_fwd_inner(
    const float* __restrict__ x, const float* __restrict__ h,
    __half2* __restrict__ buf, const cpx* __restrict__ tw) {
  __shared__ __half2 tz[128 * 18];   // z tile [n2][n1], stride 18 (bank-free cols)
  __shared__ cpx xch[4 * 512];       // per-wave exchange scratch
  __shared__ __half2 to[256 * 17];   // out tile [k2][n1l], stride 17
  __shared__ cpx w256[256];          // W256^e
  const int tid = threadIdx.x;
  const int lane = tid & 63;
  const int wid = tid >> 6;
  const int s = blockIdx.x >> 5;
  const int n1b = (blockIdx.x & 31) * 16;
  w256[tid] = tw[tid * (NFFT / 256)];
  // stage-in: 64B-granule rows (4 lanes x float4)
  const float* xp = x + (size_t)s * TLEN;
  const float* hp = h + (size_t)s * TLEN;
  {
    int a = tid & 3, q = tid >> 2;
#pragma unroll
    for (int iter = 0; iter < 2; ++iter) {
      int n2 = q + 64 * iter;
      size_t gi = (size_t)(n1b + 4 * a) + (size_t)512 * n2;
      float4 xv = *(const float4*)(xp + gi);
      float4 hv = *(const float4*)(hp + gi);
      float xs[4] = {xv.x, xv.y, xv.z, xv.w};
      float hs[4] = {hv.x, hv.y, hv.z, hv.w};
#pragma unroll
      for (int c = 0; c < 4; ++c) {
        float xb = __bfloat162float(__float2bfloat16(xs[c]));
        tz[18 * n2 + 4 * a + c] = __float22half2_rn(make_float2(xb, hs[c]));
      }
    }
  }
  __syncthreads();
  cpx* X = xch + wid * 512;
  const int f = lane >> 5;
  const int l5 = lane & 31;
  const int fb = f * 256;
  const int hh = l5 >> 2, bb = l5 & 3;  // stage-B/C lane coords
#pragma unroll
  for (int p2 = 0; p2 < 2; ++p2) {
    const int n1l = 8 * p2 + 2 * wid + f;
    const int n1 = n1b + n1l;
    // big-twiddle bases: W_N^{n1*c0}, W_N^{32*n1}  (k2 = c0 + 32*(g+2*k1q))
    cpx tbase = tw[n1 * (hh + 8 * bb)];
    cpx tstep = tw[32 * n1];
    cpx v[8];
#pragma unroll
    for (int j = 0; j < 4; ++j) v[j] = h2c(tz[18 * (32 * j + l5) + n1l]);
#pragma unroll
    for (int j = 4; j < 8; ++j) v[j] = mkc(0.f, 0.f);
    fft8<-1>(v);  // over j -> k0
    { cpx w1 = w256[l5]; cpx pw = w1;  // W256^{l5*k0}
#pragma unroll
      for (int k0 = 1; k0 < 8; ++k0) { v[k0] = cmul(v[k0], pw); pw = cmul(pw, w1); } }
#pragma unroll
    for (int k0 = 0; k0 < 8; ++k0) X[fb + 32 * k0 + (l5 ^ (4 * k0))] = v[k0];
    WFENCE();
#pragma unroll
    for (int j2 = 0; j2 < 8; ++j2) v[j2] = X[fb + 32 * hh + ((4 * j2 + bb) ^ (4 * hh))];
    fft8<-1>(v);  // over j2 -> k'0   (lane: k0 = hh, t = bb)
    { cpx w1 = w256[8 * bb]; cpx pw = w1;  // W32^{t*k'0}
#pragma unroll
      for (int kp = 1; kp < 8; ++kp) { v[kp] = cmul(v[kp], pw); pw = cmul(pw, w1); } }
    WFENCE();
#pragma unroll
    for (int kp = 0; kp < 8; ++kp) {
      int cc = kp & 3, gg = kp >> 2;
      X[fb + 128 * gg + 32 * cc + 8 * (bb ^ cc) + hh] = v[kp];
    }
    WFENCE();
    cpx tstep2 = cmul(tstep, tstep);
#pragma unroll
    for (int g = 0; g < 2; ++g) {  // lane: k0 = hh, k'0 = bb + 4g
      cpx u4[4];
#pragma unroll
      for (int t = 0; t < 4; ++t) u4[t] = X[fb + 128 * g + 32 * bb + 8 * (t ^ bb) + hh];
      fft4<-1>(u4);  // over t -> k'1
      cpx wg = (g == 0) ? tbase : cmul(tbase, tstep);
#pragma unroll
      for (int k1q = 0; k1q < 4; ++k1q) {
        int k2 = hh + 8 * bb + 32 * g + 64 * k1q;
        cpx y = cmul(u4[k1q], wg);  // * W_N^{n1*k2}
        to[17 * k2 + n1l] = c2h(y);
        wg = cmul(wg, tstep2);
      }
    }
    WFENCE();
  }
  __syncthreads();
  // out: rows k2 natural, 64B granule (4 lanes x 16B)
  {
    int c = tid & 3, q = tid >> 2;
#pragma unroll
    for (int iter = 0; iter < 4; ++iter) {
      int row = q + 64 * iter;
      __half2 h0 = to[17 * row + 4 * c + 0], h1 = to[17 * row + 4 * c + 1];
      __half2 h2v = to[17 * row + 4 * c + 2], h3 = to[17 * row + 4 * c + 3];
      int4 pk;
      pk.x = *(int*)&h0; pk.y = *(int*)&h1; pk.z = *(int*)&h2v; pk.w = *(int*)&h3;
      *(int4*)(buf + ((size_t)s * NN2 + row) * NN1 + n1b + 4 * c) = pk;
    }
  }
}

// ---------------------------------------------------------------------------
// K2: per column pair (k2, 256-k2): fwd 512-FFT over n1, Hermitian extract +
// Y=X*H, inverse 512-FFT, conj big twiddle + 1/N (folded, table-driven).
// ---------------------------------------------------------------------------
__global__ __launch_bounds__(256, 6) void k_mid(
    __half2* __restrict__ buf, const cpx* __restrict__ tw) {
  __shared__ cpx smem[4 * 576 + 512];
  cpx* w512 = smem + 4 * 576;
  const int tid = threadIdx.x;
  const int lane = tid & 63;
  const int wid = tid >> 6;
  const int s = blockIdx.x >> 6;
  const int pb = blockIdx.x & 63;
  for (int i = tid; i < 512; i += 256) w512[i] = tw[i * (NFFT / NN1)];
  const int p = 2 * pb + (wid >> 1);
  const int cidx = wid & 1;
  const int k2 = (p == 0) ? (cidx ? 128 : 0) : (cidx ? 256 - p : p);
  const int c = k2;  // natural rows
  const bool selfA = (p == 0 && cidx == 0);
  cpx* R = smem + wid * 576;
  cpx* PR = smem + ((p == 0) ? wid : (wid ^ 1)) * 576;
  __half2* colp = buf + ((size_t)s * NN2 + c) * NN1;

  const int jm = lane >> 3, mo = lane & 7;
  const int kbase = jm + 8 * mo;
  // final conj-twiddle chain: t_{r1} = tw[(kbase+64*r1)*k2] * (0.25/N)
  const float invN4 = 0.25f / (float)NFFT;  // 0.25 undoes Xf2*Hf2 = 4*X*H
  cpx tbase = cscale(tw[kbase * k2], mkc(invN4, invN4));
  cpx tstep = tw[64 * k2];

  cpx v[8];
#pragma unroll
  for (int k = 0; k < 8; ++k) v[k] = h2c(colp[lane + 64 * k]);
  __syncthreads();  // w512 ready

  fft8<-1>(v);
  { cpx w1 = w512[lane]; cpx pw = w1;
#pragma unroll
    for (int j = 1; j < 8; ++j) { v[j] = cmul(v[j], pw); pw = cmul(pw, w1); } }
#pragma unroll
  for (int j = 0; j < 8; ++j) R[64 * j + (lane ^ (8 * j))] = v[j];
  WFENCE();
#pragma unroll
  for (int m1 = 0; m1 < 8; ++m1) v[m1] = R[64 * jm + ((mo + 8 * m1) ^ (8 * jm))];
  fft8<-1>(v);
  { cpx w1 = w512[8 * mo]; cpx pw = w1;
#pragma unroll
    for (int r0 = 1; r0 < 8; ++r0) { v[r0] = cmul(v[r0], pw); pw = cmul(pw, w1); } }
  WFENCE();
#pragma unroll
  for (int r0 = 0; r0 < 8; ++r0) R[9 * (8 * jm + r0) + mo] = v[r0];
  WFENCE();
#pragma unroll
  for (int m0 = 0; m0 < 8; ++m0) v[m0] = R[9 * lane + m0];
  fft8<-1>(v);  // v[r1] = F[kbase + 64*r1]

  WFENCE();
#pragma unroll
  for (int r1 = 0; r1 < 8; ++r1) { int k = kbase + 64 * r1; R[k + (k >> 3)] = v[r1]; }
  __syncthreads();
  cpx z2[8];
#pragma unroll
  for (int r1 = 0; r1 < 8; ++r1) {
    int k = kbase + 64 * r1;
    int pk = selfA ? ((512 - k) & 511) : (511 - k);
    z2[r1] = PR[pk + (pk >> 3)];
  }
  __syncthreads();
#pragma unroll
  for (int r1 = 0; r1 < 8; ++r1) {
    cpx z1 = v[r1], q = z2[r1];
    cpx Xf2, Hf2;
    // Xf2 = (z1.x + q.x, z1.y - q.y) = 2*Xf ; Hf2 = (z1.y + q.y, q.x - z1.x) = 2*Hf
    asm("v_pk_add_f32 %0, %1, %2 neg_hi:[0,1]" : "=v"(Xf2) : "v"(z1), "v"(q));
    asm("v_pk_add_f32 %0, %1, %2 op_sel:[1,1] op_sel_hi:[0,0] neg_hi:[1,0]" : "=v"(Hf2) : "v"(z1), "v"(q));
    v[r1] = cmul(Xf2, Hf2);  // 4*X*H ; 0.25 folded into tbase
  }
#pragma unroll
  for (int r1 = 0; r1 < 8; ++r1) { int k = kbase + 64 * r1; R[k + (k >> 3)] = v[r1]; }
  WFENCE();
#pragma unroll
  for (int kk = 0; kk < 8; ++kk) { int ci = lane + 64 * kk; v[kk] = R[ci + (ci >> 3)]; }

  fft8<1>(v);
  { cpx w1 = w512[lane]; w1.y = -w1.y; cpx pw = w1;
#pragma unroll
    for (int j = 1; j < 8; ++j) { v[j] = cmul(v[j], pw); pw = cmul(pw, w1); } }
  WFENCE();
#pragma unroll
  for (int j = 0; j < 8; ++j) R[64 * j + (lane ^ (8 * j))] = v[j];
  WFENCE();
#pragma unroll
  for (int m1 = 0; m1 < 8; ++m1) v[m1] = R[64 * jm + ((mo + 8 * m1) ^ (8 * jm))];
  fft8<1>(v);
  { cpx w1 = w512[8 * mo]; w1.y = -w1.y; cpx pw = w1;
#pragma unroll
    for (int r0 = 1; r0 < 8; ++r0) { v[r0] = cmul(v[r0], pw); pw = cmul(pw, w1); } }
  WFENCE();
#pragma unroll
  for (int r0 = 0; r0 < 8; ++r0) R[9 * (8 * jm + r0) + mo] = v[r0];
  WFENCE();
#pragma unroll
  for (int m0 = 0; m0 < 8; ++m0) v[m0] = R[9 * lane + m0];
  fft8<1>(v);  // y512[kbase + 64*r1], unnormalized

  WFENCE();
#pragma unroll
  for (int r1 = 0; r1 < 8; ++r1) {
    int n1 = kbase + 64 * r1;
    cpx y = cmulc(v[r1], tbase);  // * conj(W_N^{n1*k2}) * invN/4
    R[n1 + (n1 >> 3)] = y;
    tbase = cmul(tbase, tstep);
  }
  WFENCE();
#pragma unroll
  for (int u = 0; u < 8; ++u) {
    int ci = lane + 64 * u;
    colp[ci] = c2h(R[ci + (ci >> 3)]);
  }
}

// ---------------------------------------------------------------------------
// K3: inverse FFT-256 over k2 for 16 n1 per block; write Re(y), n2 < 128.
// Exact adjoint-with-conjugate of K1's register FFT.
// ---------------------------------------------------------------------------
__global__ __launch_bounds__(256, 3) void k_inv_outer(
    const __half2* __restrict__ buf, float* __restrict__ out,
    const cpx* __restrict__ tw) {
  __shared__ __half2 ti[16 * 257];   // in tile [n1l][k2], stride 257
  __shared__ cpx xch[4 * 512];
  __shared__ float ty[128 * 17];     // y tile [n2][n1l], stride 17
  __shared__ cpx w256[256];
  const int tid = threadIdx.x;
  const int lane = tid & 63;
  const int wid = tid >> 6;
  const int s = blockIdx.x >> 5;
  const int n1b = (blockIdx.x & 31) * 16;
  w256[tid] = tw[tid * (NFFT / 256)];
  // stage-in: rows k2, 64B granule
  {
    int c = tid & 3, q = tid >> 2;
#pragma unroll
    for (int iter = 0; iter < 4; ++iter) {
      int row = q + 64 * iter;
      int4 pk = *(const int4*)(buf + ((size_t)s * NN2 + row) * NN1 + n1b + 4 * c);
      __half2 hv[4];
      *(int*)&hv[0] = pk.x; *(int*)&hv[1] = pk.y; *(int*)&hv[2] = pk.z; *(int*)&hv[3] = pk.w;
#pragma unroll
      for (int j = 0; j < 4; ++j) ti[(4 * c + j) * 257 + row] = hv[j];
    }
  }
  __syncthreads();
  cpx* X = xch + wid * 512;
  const int f = lane >> 5;
  const int l5 = lane & 31;
  const int fb = f * 256;
  const int hh = l5 >> 2, bb = l5 & 3;
#pragma unroll
  for (int p2 = 0; p2 < 2; ++p2) {
    const int n1l = 8 * p2 + 2 * wid + f;
    // load k-layout: k = hh + 8bb + 32g + 64k'1
    cpx v2[2][4];
#pragma unroll
    for (int g = 0; g < 2; ++g)
#pragma unroll
      for (int k1q = 0; k1q < 4; ++k1q)
        v2[g][k1q] = h2c(ti[n1l * 257 + hh + 8 * bb + 32 * g + 64 * k1q]);
    // ifft4 over k'1 -> t
#pragma unroll
    for (int g = 0; g < 2; ++g) fft4<1>(v2[g]);
    // E2^T: write stage-C layout -> scratch
#pragma unroll
    for (int g = 0; g < 2; ++g)
#pragma unroll
      for (int t = 0; t < 4; ++t)
        X[fb + 128 * g + 32 * bb + 8 * (t ^ bb) + hh] = v2[g][t];
    WFENCE();
    cpx v[8];
#pragma unroll
    for (int kp = 0; kp < 8; ++kp) {
      int cc = kp & 3, gg = kp >> 2;
      v[kp] = X[fb + 128 * gg + 32 * cc + 8 * (bb ^ cc) + hh];  // lane: k0=hh, t=bb
    }
    { cpx w1 = w256[8 * bb]; w1.y = -w1.y; cpx pw = w1;  // conj W32^{t*k'0}
#pragma unroll
      for (int kp = 1; kp < 8; ++kp) { v[kp] = cmul(v[kp], pw); pw = cmul(pw, w1); } }
    fft8<1>(v);  // over k'0 -> j2
    WFENCE();
#pragma unroll
    for (int j2 = 0; j2 < 8; ++j2) X[fb + 32 * hh + ((4 * j2 + bb) ^ (4 * hh))] = v[j2];
    WFENCE();
#pragma unroll
    for (int k0 = 0; k0 < 8; ++k0) v[k0] = X[fb + 32 * k0 + (l5 ^ (4 * k0))];
    { cpx w1 = w256[l5]; w1.y = -w1.y; cpx pw = w1;  // conj W256^{l5*k0}
#pragma unroll
      for (int k0 = 1; k0 < 8; ++k0) { v[k0] = cmul(v[k0], pw); pw = cmul(pw, w1); } }
    fft8<1>(v);  // over k0 -> j : v[j] = y[32j + l5]
#pragma unroll
    for (int j = 0; j < 4; ++j) ty[17 * (32 * j + l5) + n1l] = v[j].x;
    WFENCE();
  }
  __syncthreads();
  // out: y[n1 + 512*n2], n2 < 128; 2 lanes x 32B = 64B rows
  {
    int e = tid & 1, n2 = tid >> 1;
    float* op = out + (size_t)s * TLEN + (size_t)512 * n2 + n1b + 8 * e;
    float4 o0, o1;
    o0.x = ty[17 * n2 + 8 * e + 0]; o0.y = ty[17 * n2 + 8 * e + 1];
    o0.z = ty[17 * n2 + 8 * e + 2]; o0.w = ty[17 * n2 + 8 * e + 3];
    o1.x = ty[17 * n2 + 8 * e + 4]; o1.y = ty[17 * n2 + 8 * e + 5];
    o1.z = ty[17 * n2 + 8 * e + 6]; o1.w = ty[17 * n2 + 8 * e + 7];
    *(float4*)op = o0;
    *(float4*)(op + 4) = o1;
  }
}

extern "C" void kernel_launch(void* const* d_in, const int* in_sizes, int n_in,
                              void* d_out, int out_size, void* d_ws, size_t ws_size,
                              hipStream_t stream) {
  (void)n_in; (void)out_size; (void)ws_size;
  const float* x = (const float*)d_in[0];
  const float* h = (const float*)d_in[1];
  float* out = (float*)d_out;
  cpx* tw = (cpx*)d_ws;
  __half2* buf = (__half2*)((char*)d_ws + (size_t)(2 * 1024 * 1024));
  int seqs = in_sizes[0] / TLEN;  // 8*64 = 512
  k_init_tw<<<NFFT / 256, 256, 0, stream>>>(tw);
  k_fwd_inner<<<seqs * 32, 256, 0, stream>>>(x, h, buf, tw);
  k_mid<<<seqs * 64, 256, 0, stream>>>(buf, tw);
  k_inv_outer<<<seqs * 32, 256, 0, stream>>>(buf, out, tw);
}